// Round 14
// baseline (229.208 us; speedup 1.0000x reference)
//
#include <hip/hip_runtime.h>
#include <hip/hip_bf16.h>

#define BATCH 8
#define CIN   128
#define HH    256
#define WW    256
#define OUTC  64
#define INCH  1152   // CIN*9
#define HW    (HH*WW)
#define WMOD_BYTES ((size_t)BATCH * 9 * OUTC * CIN * 2)

typedef __attribute__((ext_vector_type(8)))  short short8;
typedef __attribute__((ext_vector_type(4)))  float f32x4;
typedef __attribute__((ext_vector_type(16))) float f32x16;

__device__ __forceinline__ unsigned short bf16r(float f) {
    unsigned u = __builtin_bit_cast(unsigned, f);
    u += 0x7fffu + ((u >> 16) & 1u);
    return (unsigned short)(u >> 16);
}

// wmod[b][tap][o][c] = bf16(weight[o][c*9+tap] * style[b][c*9+tap])
__global__ void __launch_bounds__(256) wmod_kernel(const float* __restrict__ weight,
                                                   const float* __restrict__ style,
                                                   unsigned short* __restrict__ wmod) {
    int i = blockIdx.x * 256 + threadIdx.x;
    if (i >= BATCH * 9 * OUTC * CIN) return;
    int c    = i & (CIN - 1);
    int rest = i >> 7;
    int o    = rest & (OUTC - 1);
    int bt   = rest >> 6;
    int tap  = bt % 9;
    int b    = bt / 9;
    int k    = c * 9 + tap;
    wmod[i] = bf16r(weight[o * INCH + k] * style[b * INCH + k]);
}

// Pair-barrier: LDS-visibility only (lgkmcnt), NO vmcnt drain -> in-flight
// VMEM (next chunk's A-loads / staging f-loads) survives the barrier.
// Safe because staging is reg->ds_write (lgkm) and VMEM lands in per-wave regs.
#define PBAR()                                              \
    do {                                                    \
        asm volatile("s_waitcnt lgkmcnt(0)" ::: "memory");  \
        __builtin_amdgcn_sched_barrier(0);                  \
        __builtin_amdgcn_s_barrier();                       \
        __builtin_amdgcn_sched_barrier(0);                  \
    } while (0)

// conv10: 32x32x16 MFMA (2x FLOP per KB of LDS B-read -> LDS port no longer
// the ceiling; kernel is HBM-bound by design).
// Block 256 thr = 4 waves; tile 64o x (8h x 32w); wave = 64o x (2h x 32w),
// acc[2][2] f32x16 = 64 f32/lane. K-chunk = 16 ch (one MFMA K), 8 chunks.
// LDS xs[2][340 px][20 shorts] (16c + 4 pad -> 10-dword stride, 2-way max
// on both ds_write_b128 and ds_read_b128). 26.6 KB total.
// Per chunk k: loadG(k+1) -> compute(k) [zero VMEM: A preloaded] ->
// loadA(k+1) -> writeG (waits f via counted vmcnt, A stays in flight) ->
// PBAR (lgkm only). One barrier per chunk; A-loads cross it in flight.
template <bool GW>
__global__ void __launch_bounds__(256, 2) conv10_kernel(
    const float* __restrict__ x,
    const unsigned short* __restrict__ wmod,
    const float* __restrict__ weight,
    const float* __restrict__ style,
    float* __restrict__ out)
{
    __shared__ __align__(16) unsigned short xs_sm[2][340 * 20];

    const int tid = threadIdx.x;           // 0..255
    const int bx  = blockIdx.x;            // 0..255: ht*8 + wt
    const int b   = blockIdx.y;
    const int h0  = (bx >> 3) * 8;
    const int w0  = (bx & 7) * 32;

    const int wv  = tid >> 6;              // wave 0..3 -> rows 2wv, 2wv+1
    const int l31 = tid & 31;
    const int kh2 = (tid >> 5) & 1;        // k-half (8 ch)

    // ---- staging geometry: 200 tasks = (cg 0..1) x (r 0..9) x (qw 0..9)
    const bool tv = tid < 200;
    const int tt  = tv ? tid : 0;
    const int cg  = tt / 100;              // 8-ch group within 16-ch chunk
    const int rem = tt % 100;
    const int sr  = rem / 10;
    const int qw  = rem % 10;
    const int sh  = h0 - 1 + sr;
    const bool hok = tv && ((unsigned)sh < HH);
    const int wl  = w0 - 4 + qw * 4;
    const int wlc = min(max(wl, 0), WW - 4);
    const int colbase = wl - (w0 - 1);
    const float* xbase = x + ((size_t)(b * CIN + cg * 8)) * HW +
                         (hok ? sh : 0) * WW + wlc;

    f32x4  f[8];                           // staged: 8 ch x 4 px
    short8 A[9][2];                        // weights: 9 taps x 2 o-halves

    auto loadG = [&](int chunk) {
        if (hok) {
#pragma unroll
            for (int j = 0; j < 8; ++j)
                f[j] = *(const f32x4*)(xbase + (size_t)(chunk * 16 + j) * HW);
        }
    };

    auto writeG = [&](unsigned short* buf) {
        if (tv) {
#pragma unroll
            for (int u = 0; u < 4; ++u) {
                int col = colbase + u;
                if (col >= 0 && col < 34) {
                    bool wok = hok && ((unsigned)(wl + u) < WW);
                    short8 sv;
#pragma unroll
                    for (int j = 0; j < 8; ++j)
                        sv[j] = wok ? (short)bf16r(f[j][u]) : (short)0;
                    int s = sr * 34 + col;
                    *(short8*)&buf[s * 20 + cg * 8] = sv;
                }
            }
        }
    };

    auto loadA = [&](int chunk) {
        if (GW) {
            const unsigned short* wb =
                wmod + ((size_t)(b * 9) * OUTC) * CIN + chunk * 16 + kh2 * 8;
#pragma unroll
            for (int tap = 0; tap < 9; ++tap)
#pragma unroll
                for (int mi = 0; mi < 2; ++mi)
                    A[tap][mi] = *(const short8*)(
                        wb + ((size_t)tap * OUTC + mi * 32 + l31) * CIN);
        } else {
#pragma unroll
            for (int tap = 0; tap < 9; ++tap)
#pragma unroll
                for (int mi = 0; mi < 2; ++mi) {
                    int o = mi * 32 + l31;
#pragma unroll
                    for (int j = 0; j < 8; ++j) {
                        int c = chunk * 16 + kh2 * 8 + j;
                        int k = c * 9 + tap;
                        A[tap][mi][j] = (short)bf16r(weight[o * INCH + k] *
                                                     style[b * INCH + k]);
                    }
                }
        }
    };

    f32x16 acc[2][2];
#pragma unroll
    for (int mi = 0; mi < 2; ++mi)
#pragma unroll
        for (int ni = 0; ni < 2; ++ni)
#pragma unroll
            for (int r = 0; r < 16; ++r) acc[mi][ni][r] = 0.f;

    auto compute = [&](const unsigned short* buf) {
#pragma unroll
        for (int kh = 0; kh < 3; ++kh)
#pragma unroll
            for (int kw = 0; kw < 3; ++kw) {
                const int tap = kh * 3 + kw;
                short8 Bv[2];
#pragma unroll
                for (int ni = 0; ni < 2; ++ni) {
                    int s = (2 * wv + ni + kh) * 34 + l31 + kw;
                    Bv[ni] = *(const short8*)&buf[s * 20 + kh2 * 8];
                }
#pragma unroll
                for (int mi = 0; mi < 2; ++mi)
#pragma unroll
                    for (int ni = 0; ni < 2; ++ni)
                        acc[mi][ni] = __builtin_amdgcn_mfma_f32_32x32x16_bf16(
                            A[tap][mi], Bv[ni], acc[mi][ni], 0, 0, 0);
            }
    };

    // ---- prologue: chunk 0
    loadG(0);
    loadA(0);
    __builtin_amdgcn_sched_barrier(0);
    writeG(xs_sm[0]);                      // waits f (A newer, stays in flight)
    PBAR();

#pragma unroll
    for (int k = 0; k < 8; ++k) {
        if (k < 7) loadG(k + 1);
        __builtin_amdgcn_sched_barrier(0);
        compute(xs_sm[k & 1]);             // zero VMEM inside
        __builtin_amdgcn_sched_barrier(0);
        if (k < 7) {
            loadA(k + 1);
            writeG(xs_sm[(k & 1) ^ 1]);
            PBAR();
        }
    }

    // ---- epilogue: 32x32 D mapping col=lane&31 (px),
    // row = (reg&3) + 8*(reg>>2) + 4*(lane>>5)
    float* op = out + ((size_t)b * OUTC) * HW + w0 + l31;
#pragma unroll
    for (int mi = 0; mi < 2; ++mi)
#pragma unroll
        for (int ni = 0; ni < 2; ++ni) {
            int h = h0 + 2 * wv + ni;
#pragma unroll
            for (int r = 0; r < 16; ++r) {
                int o = mi * 32 + (r & 3) + 8 * (r >> 2) + 4 * kh2;
                op[(size_t)o * HW + h * WW] = acc[mi][ni][r];
            }
        }
}

extern "C" void kernel_launch(void* const* d_in, const int* in_sizes, int n_in,
                              void* d_out, int out_size, void* d_ws, size_t ws_size,
                              hipStream_t stream) {
    const float* x      = (const float*)d_in[0];
    const float* style  = (const float*)d_in[1];
    const float* weight = (const float*)d_in[2];
    float* out = (float*)d_out;

    const int wmod_total = BATCH * 9 * OUTC * CIN;

    if (ws_size >= WMOD_BYTES) {
        unsigned short* wmodp = (unsigned short*)d_ws;
        wmod_kernel<<<(wmod_total + 255) / 256, 256, 0, stream>>>(weight, style, wmodp);
        conv10_kernel<true><<<dim3(256, BATCH), 256, 0, stream>>>(
            x, wmodp, nullptr, nullptr, out);
    } else {
        conv10_kernel<false><<<dim3(256, BATCH), 256, 0, stream>>>(
            x, nullptr, weight, style, out);
    }
}